// Round 8
// baseline (98.283 us; speedup 1.0000x reference)
//
#include <hip/hip_runtime.h>
#include <math.h>

#define HEADS 8
#define LVLS  4
#define PTS   8
#define NREF  4
#define DH    32
#define DD    256
#define NQc   5000
#define BATCH 2
#define NVc   13294
#define RVr   (BATCH * NVc)   // 26588
#define RQr   (BATCH * NQc)   // 10000

#define NJV 416               // value jobs: 208 row-tiles(128) x 2 col-tiles(128)
#define NJQ 474               // query jobs: 79 row-tiles(128) x 6 col-tiles(128)
#define NJOBS (NJV + NJQ)

using f16x8 = __attribute__((ext_vector_type(8))) _Float16;
using f16x4 = __attribute__((ext_vector_type(4))) _Float16;
using f32x4 = __attribute__((ext_vector_type(4))) float;
using h2    = __attribute__((ext_vector_type(2))) _Float16;

__device__ __forceinline__ int pack2(float w) {
    _Float16 h = (_Float16)w;
    h2 v = { h, h };
    return __builtin_bit_cast(int, v);
}

// ---------------------------------------------------------------------------
// Prep: transpose weights to fp16 W^T[n][k] (k stride 256).
// wtv[256][256]; wtoa[768][256] = concat(Wo^T, Wa^T)
// ---------------------------------------------------------------------------
__global__ __launch_bounds__(256) void transpose_w_kernel(
    const float* __restrict__ Wv, const float* __restrict__ Wo,
    const float* __restrict__ Wa,
    _Float16* __restrict__ wtv, _Float16* __restrict__ wto,
    _Float16* __restrict__ wta)
{
    __shared__ float tl[64][65];
    const int bid = blockIdx.x;
    const float* src; _Float16* dst; int N, kt, nt;
    if (bid < 16)      { src = Wv; dst = wtv; N = 256; kt = bid & 3;        nt = bid >> 2; }
    else if (bid < 48) { src = Wo; dst = wto; N = 512; kt = (bid - 16) & 3; nt = (bid - 16) >> 2; }
    else               { src = Wa; dst = wta; N = 256; kt = (bid - 48) & 3; nt = (bid - 48) >> 2; }
    const int k0 = kt * 64, n0 = nt * 64;
    const int c  = threadIdx.x & 63, r4 = threadIdx.x >> 6;
    #pragma unroll
    for (int i = 0; i < 16; ++i) {
        const int r = r4 + i * 4;
        tl[r][c] = src[(size_t)(k0 + r) * N + n0 + c];
    }
    __syncthreads();
    #pragma unroll
    for (int i = 0; i < 16; ++i) {
        const int r = r4 + i * 4;   // n-local
        dst[(size_t)(n0 + r) * 256 + k0 + c] = (_Float16)tl[c][r];
    }
}

// ---------------------------------------------------------------------------
// Uber MFMA GEMM, 2-phase pipelined: one dispatch, job table by blockIdx.
//   job < NJV : v_f16 (HEAD-MAJOR: [b][head][NV][32] fp16) = value @ Wv + bv
//   else      : offa[RQ][768](fp16)  = query @ [Wo|Wa] + [bo|ba]
// Tile 128x128, BK=64, 4 waves (2x2), wave tile 64x64, acc 4x4 (32 MFMA/chunk).
// Double-buffered LDS; per K-step: {stage B[t+1] gload_lds + issue A[t+1]
// global loads} || {ds_read + MFMA on buf[t]} ; convert+ds_write A[t+1];
// ONE __syncthreads per K-step.
// ---------------------------------------------------------------------------
__global__ __launch_bounds__(256) void gemm_uber_kernel(
    const float* __restrict__ value, const float* __restrict__ query,
    const _Float16* __restrict__ wtv, const _Float16* __restrict__ wtoa,
    const float* __restrict__ bv, const float* __restrict__ bo,
    const float* __restrict__ ba,
    _Float16* __restrict__ v_f16, _Float16* __restrict__ offa)
{
    __shared__ _Float16 aL[2][128][72];   // 144B row stride
    __shared__ _Float16 bL[2][128][64];   // [n][k] linear, 16B-slot swizzled

    const int t    = threadIdx.x;
    const int lane = t & 63;
    const int wid  = t >> 6;
    const int wr   = wid >> 1;
    const int wc   = wid & 1;

    const int job = blockIdx.x;
    const bool isV = job < NJV;
    const float* A; const _Float16* WT; int R, r0, ct;
    if (isV) { A = value; WT = wtv;  R = RVr; r0 = (job >> 1) * 128;  ct = job & 1; }
    else     { const int j2 = job - NJV;
               A = query; WT = wtoa; R = RQr; r0 = (j2 / 6) * 128;    ct = j2 % 6; }
    const int c0 = ct * 128;

    f32x4 acc[4][4] = {};

    const int sr = t >> 4;            // 0..15
    const int sc = (t & 15) * 4;      // 0..60
    const int brow  = lane >> 3;                 // 0..7 row-in-chunk
    const int bslot = (lane & 7) ^ brow;         // swizzled 16B source slot
    const int lm  = lane & 15;
    const int khi = lane >> 4;

    float4 ap[8];

    // ---- prologue: stage chunk 0 ----
    #pragma unroll
    for (int cch = 0; cch < 4; ++cch) {
        const int ch  = wid * 4 + cch;
        const int row = ch * 8 + brow;
        const _Float16* src = WT + (size_t)(c0 + row) * 256 + 0 + bslot * 8;
        char* ldst = (char*)&bL[0][0][0] + ch * 1024;
        __builtin_amdgcn_global_load_lds(
            (const __attribute__((address_space(1))) void*)src,
            (__attribute__((address_space(3))) void*)ldst, 16, 0, 0);
    }
    #pragma unroll
    for (int i = 0; i < 8; ++i) {
        const int gr = r0 + sr + i * 16;
        ap[i] = (gr < R) ? *(const float4*)&A[(size_t)gr * 256 + sc]
                         : make_float4(0.f, 0.f, 0.f, 0.f);
    }
    #pragma unroll
    for (int i = 0; i < 8; ++i) {
        f16x4 pk = { (_Float16)ap[i].x, (_Float16)ap[i].y,
                     (_Float16)ap[i].z, (_Float16)ap[i].w };
        *(f16x4*)&aL[0][sr + i * 16][sc] = pk;
    }
    __syncthreads();

    // ---- main loop: 4 K-chunks, one barrier each ----
    #pragma unroll
    for (int tk = 0; tk < 4; ++tk) {
        const int cur = tk & 1;
        if (tk < 3) {
            const int kc = (tk + 1) * 64;
            #pragma unroll
            for (int cch = 0; cch < 4; ++cch) {
                const int ch  = wid * 4 + cch;
                const int row = ch * 8 + brow;
                const _Float16* src = WT + (size_t)(c0 + row) * 256 + kc + bslot * 8;
                char* ldst = (char*)&bL[cur ^ 1][0][0] + ch * 1024;
                __builtin_amdgcn_global_load_lds(
                    (const __attribute__((address_space(1))) void*)src,
                    (__attribute__((address_space(3))) void*)ldst, 16, 0, 0);
            }
            #pragma unroll
            for (int i = 0; i < 8; ++i) {
                const int gr = r0 + sr + i * 16;
                ap[i] = (gr < R) ? *(const float4*)&A[(size_t)gr * 256 + kc + sc]
                                 : make_float4(0.f, 0.f, 0.f, 0.f);
            }
        }

        const char* bB = (const char*)&bL[cur][0][0];
        #pragma unroll
        for (int kk = 0; kk < 2; ++kk) {
            f16x8 bfrag[4];
            #pragma unroll
            for (int nf = 0; nf < 4; ++nf) {
                const int row  = wc * 64 + nf * 16 + lm;
                const int slot = kk * 4 + khi;
                bfrag[nf] = *(const f16x8*)(bB + row * 128 + ((slot ^ (row & 7)) << 4));
            }
            #pragma unroll
            for (int m = 0; m < 4; ++m) {
                const f16x8 afrag = *(const f16x8*)&aL[cur][wr * 64 + m * 16 + lm][kk * 32 + khi * 8];
                #pragma unroll
                for (int nf = 0; nf < 4; ++nf)
                    acc[m][nf] = __builtin_amdgcn_mfma_f32_16x16x32_f16(
                        afrag, bfrag[nf], acc[m][nf], 0, 0, 0);
            }
        }

        if (tk < 3) {
            #pragma unroll
            for (int i = 0; i < 8; ++i) {
                f16x4 pk = { (_Float16)ap[i].x, (_Float16)ap[i].y,
                             (_Float16)ap[i].z, (_Float16)ap[i].w };
                *(f16x4*)&aL[cur ^ 1][sr + i * 16][sc] = pk;
            }
        }
        __syncthreads();
    }

    // ---- epilogue ----
    const int lq = lane >> 4;
    if (isV) {
        #pragma unroll
        for (int nf = 0; nf < 4; ++nf) {
            const int col = c0 + wc * 64 + nf * 16 + lm;   // h*32 + ch
            const int hh = col >> 5, ch = col & 31;
            const float bb = bv[col];
            #pragma unroll
            for (int m = 0; m < 4; ++m)
                #pragma unroll
                for (int r = 0; r < 4; ++r) {
                    const int row = r0 + wr * 64 + m * 16 + lq * 4 + r;
                    if (row < RVr) {
                        const int b   = (row >= NVc) ? 1 : 0;
                        const int pix = row - b * NVc;
                        v_f16[(((size_t)(b * HEADS + hh) * NVc) + pix) * 32 + ch] =
                            (_Float16)(acc[m][nf][r] + bb);
                    }
                }
        }
    } else {
        #pragma unroll
        for (int nf = 0; nf < 4; ++nf) {
            const int col = c0 + wc * 64 + nf * 16 + lm;
            const float bb = (col < 512) ? bo[col] : ba[col - 512];
            #pragma unroll
            for (int m = 0; m < 4; ++m)
                #pragma unroll
                for (int r = 0; r < 4; ++r) {
                    const int row = r0 + wr * 64 + m * 16 + lq * 4 + r;
                    if (row < RQr) offa[(size_t)row * 768 + col] = (_Float16)(acc[m][nf][r] + bb);
                }
        }
    }
}

// ---------------------------------------------------------------------------
// Sampling: one wave per (b, q, h). Level shapes/starts hardcoded (square).
// v is HEAD-MAJOR: [b][head][pixel][32ch] fp16 -> pixel stride 64B; the x0/x1
// corners of a sample are ADJACENT 64B blocks.
// Stage 1: lanes j=0..31 per (level,point); halves split corner rows (y0/y1);
// each stores {byte addr, packed half2 weight} int2 into padded LDS.
// Stage 2: 8 iters; lane = (po<<4)|(corner<<2)|octet; 16B fp16 gather;
// pk_fma with fp16 accs; packed 4-level shfl reduction; f32 store.
// ---------------------------------------------------------------------------
__global__ __launch_bounds__(256) void sample_kernel(
    const _Float16* __restrict__ v,    // (B*HEADS*NV) x 32 fp16, head-major
    const _Float16* __restrict__ offa, // (B*NQ) x 768 fp16: [0:512) offsets, [512:768) logits
    const float* __restrict__ refp,    // (B, NQ, NREF, 2)
    float* __restrict__ out)           // (B, NQ, 256)
{
    __shared__ int2 swa[4][32][5];     // {byte addr, packed h2 weight}, padded

    const int t    = threadIdx.x;
    const int wv   = t >> 6;
    const int lane = t & 63;
    const int j    = lane & 31;
    const int half = lane >> 5;

    const int task = blockIdx.x * 4 + wv;       // B*NQ*HEADS tasks
    const int h  = task & 7;
    const int bq = task >> 3;
    const int b  = bq / NQc;

    // ---- stage 1 ----
    {
        const int l = j >> 3;
        const int p = j & 7;
        const int r = p & 3;
        const int   Wi = (l == 0) ? 100 : (l == 1) ? 50 : (l == 2) ? 25 : 13;
        const float Wf = (float)Wi;
        const int   st = (l == 0) ? 0 : (l == 1) ? 10000 : (l == 2) ? 12500 : 13125;

        const _Float16* orow = offa + (size_t)bq * 768;
        const float lg = (float)orow[512 + h * 32 + j];
        const float e  = __expf(lg);    // |lg| small: no max-subtraction needed
        float s = e;
        #pragma unroll
        for (int mask = 16; mask >= 1; mask >>= 1)
            s += __shfl_xor(s, mask, 64);
        const float aw = __fdividef(e, s);

        const h2 oxy = *(const h2*)&orow[h * 64 + j * 2];
        const float2 rxy = *(const float2*)&refp[((size_t)bq * NREF + r) * 2];

        const float x = rxy.x * Wf + (float)oxy[0] - 0.5f;
        const float y = rxy.y * Wf + (float)oxy[1] - 0.5f;
        const float x0f = floorf(x), y0f = floorf(y);
        const float dx = x - x0f, dy = y - y0f;
        const int x0 = (int)x0f, y0 = (int)y0f;
        const int x1 = x0 + 1;

        // own corner row for this half
        const int   yy = y0 + half;
        const float fy = (half ? dy : 1.f - dy) * aw;
        const bool  vy = (yy >= 0) && (yy < Wi);
        const int   yc = min(max(yy, 0), Wi - 1);

        const bool vx0 = (x0 >= 0) && (x0 < Wi);
        const bool vx1 = (x1 >= 0) && (x1 < Wi);
        const int  xc0 = min(max(x0, 0), Wi - 1);
        const int  xc1 = min(max(x1, 0), Wi - 1);

        // head-major: pixel stride 64B
        const int bb   = ((b * HEADS + h) * NVc + st) * 64;   // byte base
        const int rowb = bb + yc * Wi * 64;
        const float wA = (vx0 && vy) ? (1.f - dx) * fy : 0.f;
        const float wB = (vx1 && vy) ? dx * fy : 0.f;

        swa[wv][j][half * 2 + 0] = make_int2(rowb + (xc0 << 6), pack2(wA));
        swa[wv][j][half * 2 + 1] = make_int2(rowb + (xc1 << 6), pack2(wB));
    }

    // ---- stage 2 ----
    const int po  = lane >> 4;        // point offset 0..3
    const int c   = (lane >> 2) & 3;  // corner
    const int cqb = (lane & 3) * 16;  // channel-octet byte offset within 64B

    h2 acc0 = {}, acc1 = {}, acc2 = {}, acc3 = {};
    #pragma unroll
    for (int it = 0; it < 8; ++it) {
        const int2 aw2 = swa[wv][it * 4 + po][c];
        const h2 w2 = __builtin_bit_cast(h2, aw2.y);
        const f16x8 val = *(const f16x8*)((const char*)v + aw2.x + cqb);
        acc0 += w2 * (h2){ val[0], val[1] };
        acc1 += w2 * (h2){ val[2], val[3] };
        acc2 += w2 * (h2){ val[4], val[5] };
        acc3 += w2 * (h2){ val[6], val[7] };
    }

    #pragma unroll
    for (int mask = 4; mask <= 32; mask <<= 1) {
        acc0 += __builtin_bit_cast(h2, __shfl_xor(__builtin_bit_cast(int, acc0), mask, 64));
        acc1 += __builtin_bit_cast(h2, __shfl_xor(__builtin_bit_cast(int, acc1), mask, 64));
        acc2 += __builtin_bit_cast(h2, __shfl_xor(__builtin_bit_cast(int, acc2), mask, 64));
        acc3 += __builtin_bit_cast(h2, __shfl_xor(__builtin_bit_cast(int, acc3), mask, 64));
    }

    if (lane < 4) {
        float* dst = &out[(size_t)bq * 256 + h * 32 + lane * 8];
        *(float4*)(dst + 0) = make_float4((float)acc0[0], (float)acc0[1],
                                          (float)acc1[0], (float)acc1[1]);
        *(float4*)(dst + 4) = make_float4((float)acc2[0], (float)acc2[1],
                                          (float)acc3[0], (float)acc3[1]);
    }
}

extern "C" void kernel_launch(void* const* d_in, const int* in_sizes, int n_in,
                              void* d_out, int out_size, void* d_ws, size_t ws_size,
                              hipStream_t stream)
{
    const float* query  = (const float*)d_in[0];
    // d_in[1] = key (unused by the reference)
    const float* value  = (const float*)d_in[2];
    const float* refp   = (const float*)d_in[3];
    const float* Wv     = (const float*)d_in[6];
    const float* bv     = (const float*)d_in[7];
    const float* Wo     = (const float*)d_in[8];
    const float* bo     = (const float*)d_in[9];
    const float* Wa     = (const float*)d_in[10];
    const float* ba     = (const float*)d_in[11];
    float* out = (float*)d_out;

    _Float16* v_f16 = (_Float16*)d_ws;                          // RV*256 f16 (head-major)
    _Float16* offa  = v_f16 + (size_t)RVr * 256;                // RQ*768 f16
    _Float16* wtv   = offa + (size_t)RQr * 768;                 // 256*256 f16
    _Float16* wtoa  = wtv + 256 * 256;                          // 768*256 f16

    transpose_w_kernel<<<dim3(64), 256, 0, stream>>>(
        Wv, Wo, Wa, wtv, wtoa, wtoa + 512 * 256);

    gemm_uber_kernel<<<dim3(NJOBS), 256, 0, stream>>>(
        value, query, wtv, wtoa, bv, bo, ba, v_f16, offa);

    sample_kernel<<<dim3(RQr * HEADS / 4), 256, 0, stream>>>(
        v_f16, offa, refp, out);
}

// Round 9
// 97.734 us; speedup vs baseline: 1.0056x; 1.0056x over previous
//
#include <hip/hip_runtime.h>
#include <math.h>

#define HEADS 8
#define LVLS  4
#define PTS   8
#define NREF  4
#define DH    32
#define DD    256
#define NQc   5000
#define BATCH 2
#define NVc   13294
#define RVr   (BATCH * NVc)   // 26588
#define RQr   (BATCH * NQc)   // 10000

#define NJV 416               // value jobs: 208 row-tiles(128) x 2 col-tiles(128)
#define NJQ 474               // query jobs: 79 row-tiles(128) x 6 col-tiles(128)
#define NJOBS (NJV + NJQ)

using f16x8 = __attribute__((ext_vector_type(8))) _Float16;
using f16x4 = __attribute__((ext_vector_type(4))) _Float16;
using f32x4 = __attribute__((ext_vector_type(4))) float;
using h2    = __attribute__((ext_vector_type(2))) _Float16;

__device__ __forceinline__ int pack2(float w) {
    _Float16 h = (_Float16)w;
    h2 v = { h, h };
    return __builtin_bit_cast(int, v);
}

// ---------------------------------------------------------------------------
// Prep: transpose weights to fp16 W^T[n][k] (k stride 256).
// wtv[256][256]; wtoa[768][256] = concat(Wo^T, Wa^T)
// ---------------------------------------------------------------------------
__global__ __launch_bounds__(256) void transpose_w_kernel(
    const float* __restrict__ Wv, const float* __restrict__ Wo,
    const float* __restrict__ Wa,
    _Float16* __restrict__ wtv, _Float16* __restrict__ wto,
    _Float16* __restrict__ wta)
{
    __shared__ float tl[64][65];
    const int bid = blockIdx.x;
    const float* src; _Float16* dst; int N, kt, nt;
    if (bid < 16)      { src = Wv; dst = wtv; N = 256; kt = bid & 3;        nt = bid >> 2; }
    else if (bid < 48) { src = Wo; dst = wto; N = 512; kt = (bid - 16) & 3; nt = (bid - 16) >> 2; }
    else               { src = Wa; dst = wta; N = 256; kt = (bid - 48) & 3; nt = (bid - 48) >> 2; }
    const int k0 = kt * 64, n0 = nt * 64;
    const int c  = threadIdx.x & 63, r4 = threadIdx.x >> 6;
    #pragma unroll
    for (int i = 0; i < 16; ++i) {
        const int r = r4 + i * 4;
        tl[r][c] = src[(size_t)(k0 + r) * N + n0 + c];
    }
    __syncthreads();
    #pragma unroll
    for (int i = 0; i < 16; ++i) {
        const int r = r4 + i * 4;   // n-local
        dst[(size_t)(n0 + r) * 256 + k0 + c] = (_Float16)tl[c][r];
    }
}

// ---------------------------------------------------------------------------
// Uber MFMA GEMM: one dispatch, job table by blockIdx.
//   job < NJV : v_f16 (HEAD-MAJOR: [b][head][NV][32] fp16) = value @ Wv + bv
//   else      : offa[RQ][768](fp16)  = query @ [Wo|Wa] + [bo|ba]
// Tile 128x128, BK=64, 4 waves (2x2), wave tile 64x64, acc 4x4 (32 MFMA/chunk).
// SINGLE-buffered LDS (34.8KB -> 4 blocks/CU, 16 waves/CU): R8's 68KB dbuf
// collapsed occupancy to 2 blocks/CU and regressed 2x. 2 barriers per chunk.
// B via global_load_lds w=16, XOR-swizzled source; A reg-staged fp32->fp16.
// ---------------------------------------------------------------------------
__global__ __launch_bounds__(256) void gemm_uber_kernel(
    const float* __restrict__ value, const float* __restrict__ query,
    const _Float16* __restrict__ wtv, const _Float16* __restrict__ wtoa,
    const float* __restrict__ bv, const float* __restrict__ bo,
    const float* __restrict__ ba,
    _Float16* __restrict__ v_f16, _Float16* __restrict__ offa)
{
    __shared__ _Float16 aL[128][72];   // 144B row stride
    __shared__ _Float16 bL[128][64];   // [n][k] linear, 16B-slot swizzled

    const int t    = threadIdx.x;
    const int lane = t & 63;
    const int wid  = t >> 6;
    const int wr   = wid >> 1;
    const int wc   = wid & 1;

    const int job = blockIdx.x;
    const bool isV = job < NJV;
    const float* A; const _Float16* WT; int R, r0, ct;
    if (isV) { A = value; WT = wtv;  R = RVr; r0 = (job >> 1) * 128;  ct = job & 1; }
    else     { const int j2 = job - NJV;
               A = query; WT = wtoa; R = RQr; r0 = (j2 / 6) * 128;    ct = j2 % 6; }
    const int c0 = ct * 128;

    f32x4 acc[4][4] = {};

    const int sr = t >> 4;            // 0..15
    const int sc = (t & 15) * 4;      // 0..60
    const int brow  = lane >> 3;                 // 0..7 row-in-chunk
    const int bslot = (lane & 7) ^ brow;         // swizzled 16B source slot
    const int lm  = lane & 15;
    const int khi = lane >> 4;

    for (int kc = 0; kc < 256; kc += 64) {
        __syncthreads();
        // B tile: 128n x 64k fp16 = 16KB = 16 chunks of 1KB; wave owns 4.
        #pragma unroll
        for (int cch = 0; cch < 4; ++cch) {
            const int ch  = wid * 4 + cch;
            const int row = ch * 8 + brow;
            const _Float16* src = WT + (size_t)(c0 + row) * 256 + kc + bslot * 8;
            char* ldst = (char*)&bL[0][0] + ch * 1024;
            __builtin_amdgcn_global_load_lds(
                (const __attribute__((address_space(1))) void*)src,
                (__attribute__((address_space(3))) void*)ldst, 16, 0, 0);
        }
        // A tile: 128 x 64 fp32, coalesced float4, convert, 8B LDS writes
        #pragma unroll
        for (int i = 0; i < 8; ++i) {
            const int row = sr + i * 16;
            const int gr  = r0 + row;
            float4 vv = make_float4(0.f, 0.f, 0.f, 0.f);
            if (gr < R) vv = *(const float4*)&A[(size_t)gr * 256 + kc + sc];
            f16x4 pk = { (_Float16)vv.x, (_Float16)vv.y, (_Float16)vv.z, (_Float16)vv.w };
            *(f16x4*)&aL[row][sc] = pk;
        }
        __syncthreads();

        const char* bB = (const char*)&bL[0][0];
        #pragma unroll
        for (int kk = 0; kk < 2; ++kk) {
            f16x8 bfrag[4];
            #pragma unroll
            for (int nf = 0; nf < 4; ++nf) {
                const int row  = wc * 64 + nf * 16 + lm;
                const int slot = kk * 4 + khi;
                bfrag[nf] = *(const f16x8*)(bB + row * 128 + ((slot ^ (row & 7)) << 4));
            }
            #pragma unroll
            for (int m = 0; m < 4; ++m) {
                const f16x8 afrag = *(const f16x8*)&aL[wr * 64 + m * 16 + lm][kk * 32 + khi * 8];
                #pragma unroll
                for (int nf = 0; nf < 4; ++nf)
                    acc[m][nf] = __builtin_amdgcn_mfma_f32_16x16x32_f16(
                        afrag, bfrag[nf], acc[m][nf], 0, 0, 0);
            }
        }
    }

    // ---- epilogue ----
    const int lq = lane >> 4;
    if (isV) {
        #pragma unroll
        for (int nf = 0; nf < 4; ++nf) {
            const int col = c0 + wc * 64 + nf * 16 + lm;   // h*32 + ch
            const int hh = col >> 5, ch = col & 31;
            const float bb = bv[col];
            #pragma unroll
            for (int m = 0; m < 4; ++m)
                #pragma unroll
                for (int r = 0; r < 4; ++r) {
                    const int row = r0 + wr * 64 + m * 16 + lq * 4 + r;
                    if (row < RVr) {
                        const int b   = (row >= NVc) ? 1 : 0;
                        const int pix = row - b * NVc;
                        v_f16[(((size_t)(b * HEADS + hh) * NVc) + pix) * 32 + ch] =
                            (_Float16)(acc[m][nf][r] + bb);
                    }
                }
        }
    } else {
        #pragma unroll
        for (int nf = 0; nf < 4; ++nf) {
            const int col = c0 + wc * 64 + nf * 16 + lm;
            const float bb = (col < 512) ? bo[col] : ba[col - 512];
            #pragma unroll
            for (int m = 0; m < 4; ++m)
                #pragma unroll
                for (int r = 0; r < 4; ++r) {
                    const int row = r0 + wr * 64 + m * 16 + lq * 4 + r;
                    if (row < RQr) offa[(size_t)row * 768 + col] = (_Float16)(acc[m][nf][r] + bb);
                }
        }
    }
}

// ---------------------------------------------------------------------------
// Sampling: one wave per (b, q, h). Level shapes/starts hardcoded (square).
// v is HEAD-MAJOR: [b][head][pixel][32ch] fp16 -> pixel stride 64B; the x0/x1
// corners of a sample are ADJACENT 64B blocks.
// Stage 1: lanes j=0..31 per (level,point); halves split corner rows (y0/y1);
// each stores {byte addr, packed half2 weight} int2 into padded LDS.
// Stage 2: 8 iters; lane = (po<<4)|(corner<<2)|octet; 16B fp16 gather;
// pk_fma with fp16 accs; packed 4-level shfl reduction; f32 store.
// ---------------------------------------------------------------------------
__global__ __launch_bounds__(256) void sample_kernel(
    const _Float16* __restrict__ v,    // (B*HEADS*NV) x 32 fp16, head-major
    const _Float16* __restrict__ offa, // (B*NQ) x 768 fp16: [0:512) offsets, [512:768) logits
    const float* __restrict__ refp,    // (B, NQ, NREF, 2)
    float* __restrict__ out)           // (B, NQ, 256)
{
    __shared__ int2 swa[4][32][5];     // {byte addr, packed h2 weight}, padded

    const int t    = threadIdx.x;
    const int wv   = t >> 6;
    const int lane = t & 63;
    const int j    = lane & 31;
    const int half = lane >> 5;

    const int task = blockIdx.x * 4 + wv;       // B*NQ*HEADS tasks
    const int h  = task & 7;
    const int bq = task >> 3;
    const int b  = bq / NQc;

    // ---- stage 1 ----
    {
        const int l = j >> 3;
        const int p = j & 7;
        const int r = p & 3;
        const int   Wi = (l == 0) ? 100 : (l == 1) ? 50 : (l == 2) ? 25 : 13;
        const float Wf = (float)Wi;
        const int   st = (l == 0) ? 0 : (l == 1) ? 10000 : (l == 2) ? 12500 : 13125;

        const _Float16* orow = offa + (size_t)bq * 768;
        const float lg = (float)orow[512 + h * 32 + j];
        const float e  = __expf(lg);    // |lg| small: no max-subtraction needed
        float s = e;
        #pragma unroll
        for (int mask = 16; mask >= 1; mask >>= 1)
            s += __shfl_xor(s, mask, 64);
        const float aw = __fdividef(e, s);

        const h2 oxy = *(const h2*)&orow[h * 64 + j * 2];
        const float2 rxy = *(const float2*)&refp[((size_t)bq * NREF + r) * 2];

        const float x = rxy.x * Wf + (float)oxy[0] - 0.5f;
        const float y = rxy.y * Wf + (float)oxy[1] - 0.5f;
        const float x0f = floorf(x), y0f = floorf(y);
        const float dx = x - x0f, dy = y - y0f;
        const int x0 = (int)x0f, y0 = (int)y0f;
        const int x1 = x0 + 1;

        // own corner row for this half
        const int   yy = y0 + half;
        const float fy = (half ? dy : 1.f - dy) * aw;
        const bool  vy = (yy >= 0) && (yy < Wi);
        const int   yc = min(max(yy, 0), Wi - 1);

        const bool vx0 = (x0 >= 0) && (x0 < Wi);
        const bool vx1 = (x1 >= 0) && (x1 < Wi);
        const int  xc0 = min(max(x0, 0), Wi - 1);
        const int  xc1 = min(max(x1, 0), Wi - 1);

        // head-major: pixel stride 64B
        const int bb   = ((b * HEADS + h) * NVc + st) * 64;   // byte base
        const int rowb = bb + yc * Wi * 64;
        const float wA = (vx0 && vy) ? (1.f - dx) * fy : 0.f;
        const float wB = (vx1 && vy) ? dx * fy : 0.f;

        swa[wv][j][half * 2 + 0] = make_int2(rowb + (xc0 << 6), pack2(wA));
        swa[wv][j][half * 2 + 1] = make_int2(rowb + (xc1 << 6), pack2(wB));
    }

    // ---- stage 2 ----
    const int po  = lane >> 4;        // point offset 0..3
    const int c   = (lane >> 2) & 3;  // corner
    const int cqb = (lane & 3) * 16;  // channel-octet byte offset within 64B

    h2 acc0 = {}, acc1 = {}, acc2 = {}, acc3 = {};
    #pragma unroll
    for (int it = 0; it < 8; ++it) {
        const int2 aw2 = swa[wv][it * 4 + po][c];
        const h2 w2 = __builtin_bit_cast(h2, aw2.y);
        const f16x8 val = *(const f16x8*)((const char*)v + aw2.x + cqb);
        acc0 += w2 * (h2){ val[0], val[1] };
        acc1 += w2 * (h2){ val[2], val[3] };
        acc2 += w2 * (h2){ val[4], val[5] };
        acc3 += w2 * (h2){ val[6], val[7] };
    }

    #pragma unroll
    for (int mask = 4; mask <= 32; mask <<= 1) {
        acc0 += __builtin_bit_cast(h2, __shfl_xor(__builtin_bit_cast(int, acc0), mask, 64));
        acc1 += __builtin_bit_cast(h2, __shfl_xor(__builtin_bit_cast(int, acc1), mask, 64));
        acc2 += __builtin_bit_cast(h2, __shfl_xor(__builtin_bit_cast(int, acc2), mask, 64));
        acc3 += __builtin_bit_cast(h2, __shfl_xor(__builtin_bit_cast(int, acc3), mask, 64));
    }

    if (lane < 4) {
        float* dst = &out[(size_t)bq * 256 + h * 32 + lane * 8];
        *(float4*)(dst + 0) = make_float4((float)acc0[0], (float)acc0[1],
                                          (float)acc1[0], (float)acc1[1]);
        *(float4*)(dst + 4) = make_float4((float)acc2[0], (float)acc2[1],
                                          (float)acc3[0], (float)acc3[1]);
    }
}

extern "C" void kernel_launch(void* const* d_in, const int* in_sizes, int n_in,
                              void* d_out, int out_size, void* d_ws, size_t ws_size,
                              hipStream_t stream)
{
    const float* query  = (const float*)d_in[0];
    // d_in[1] = key (unused by the reference)
    const float* value  = (const float*)d_in[2];
    const float* refp   = (const float*)d_in[3];
    const float* Wv     = (const float*)d_in[6];
    const float* bv     = (const float*)d_in[7];
    const float* Wo     = (const float*)d_in[8];
    const float* bo     = (const float*)d_in[9];
    const float* Wa     = (const float*)d_in[10];
    const float* ba     = (const float*)d_in[11];
    float* out = (float*)d_out;

    _Float16* v_f16 = (_Float16*)d_ws;                          // RV*256 f16 (head-major)
    _Float16* offa  = v_f16 + (size_t)RVr * 256;                // RQ*768 f16
    _Float16* wtv   = offa + (size_t)RQr * 768;                 // 256*256 f16
    _Float16* wtoa  = wtv + 256 * 256;                          // 768*256 f16

    transpose_w_kernel<<<dim3(64), 256, 0, stream>>>(
        Wv, Wo, Wa, wtv, wtoa, wtoa + 512 * 256);

    gemm_uber_kernel<<<dim3(NJOBS), 256, 0, stream>>>(
        value, query, wtv, wtoa, bv, bo, ba, v_f16, offa);

    sample_kernel<<<dim3(RQr * HEADS / 4), 256, 0, stream>>>(
        v_f16, offa, refp, out);
}

// Round 10
// 81.954 us; speedup vs baseline: 1.1992x; 1.1925x over previous
//
#include <hip/hip_runtime.h>
#include <math.h>

#define HEADS 8
#define LVLS  4
#define PTS   8
#define NREF  4
#define DH    32
#define DD    256
#define NQc   5000
#define BATCH 2
#define NVc   13294
#define RVr   (BATCH * NVc)   // 26588
#define RQr   (BATCH * NQc)   // 10000

#define NJV 832               // value jobs: 416 row-tiles(64) x 2 col-tiles(128)
#define NJQ 942               // query jobs: 157 row-tiles(64) x 6 col-tiles(128)
#define NJOBS (NJV + NJQ)

using f16x8 = __attribute__((ext_vector_type(8))) _Float16;
using f16x4 = __attribute__((ext_vector_type(4))) _Float16;
using f32x4 = __attribute__((ext_vector_type(4))) float;
using h2    = __attribute__((ext_vector_type(2))) _Float16;

__device__ __forceinline__ int pack2(float w) {
    _Float16 h = (_Float16)w;
    h2 v = { h, h };
    return __builtin_bit_cast(int, v);
}

// ---------------------------------------------------------------------------
// Prep: transpose weights to fp16 W^T[n][k] (k stride 256).
// wtv[256][256]; wtoa[768][256] = concat(Wo^T, Wa^T)
// ---------------------------------------------------------------------------
__global__ __launch_bounds__(256) void transpose_w_kernel(
    const float* __restrict__ Wv, const float* __restrict__ Wo,
    const float* __restrict__ Wa,
    _Float16* __restrict__ wtv, _Float16* __restrict__ wto,
    _Float16* __restrict__ wta)
{
    __shared__ float tl[64][65];
    const int bid = blockIdx.x;
    const float* src; _Float16* dst; int N, kt, nt;
    if (bid < 16)      { src = Wv; dst = wtv; N = 256; kt = bid & 3;        nt = bid >> 2; }
    else if (bid < 48) { src = Wo; dst = wto; N = 512; kt = (bid - 16) & 3; nt = (bid - 16) >> 2; }
    else               { src = Wa; dst = wta; N = 256; kt = (bid - 48) & 3; nt = (bid - 48) >> 2; }
    const int k0 = kt * 64, n0 = nt * 64;
    const int c  = threadIdx.x & 63, r4 = threadIdx.x >> 6;
    #pragma unroll
    for (int i = 0; i < 16; ++i) {
        const int r = r4 + i * 4;
        tl[r][c] = src[(size_t)(k0 + r) * N + n0 + c];
    }
    __syncthreads();
    #pragma unroll
    for (int i = 0; i < 16; ++i) {
        const int r = r4 + i * 4;   // n-local
        dst[(size_t)(n0 + r) * 256 + k0 + c] = (_Float16)tl[c][r];
    }
}

// ---------------------------------------------------------------------------
// Uber MFMA GEMM (R7-proven structure): one dispatch, job table by blockIdx.
//   job < NJV : v_f16 (HEAD-MAJOR: [b][head][NV][32] fp16) = value @ Wv + bv
//   else      : offa[RQ][768](fp16)  = query @ [Wo|Wa] + [bo|ba]
// Tile 64x128, BK=64, 4 waves (2x2), wave tile 32x64, acc 2x4.
// 1774 blocks (~7/CU), 25.6KB LDS (6 resident blocks/CU): R8/R9 showed this
// small-K GEMM is latency-bound -> block-level TLP beats per-block density
// (128x128 variants: 890 blocks, 2x slower).
// B via global_load_lds w=16, XOR-swizzled source; A reg-staged fp32->fp16.
// ---------------------------------------------------------------------------
__global__ __launch_bounds__(256) void gemm_uber_kernel(
    const float* __restrict__ value, const float* __restrict__ query,
    const _Float16* __restrict__ wtv, const _Float16* __restrict__ wtoa,
    const float* __restrict__ bv, const float* __restrict__ bo,
    const float* __restrict__ ba,
    _Float16* __restrict__ v_f16, _Float16* __restrict__ offa)
{
    __shared__ _Float16 aL[64][72];    // 144B row stride
    __shared__ _Float16 bL[128][64];   // [n][k] linear, 16B-slot swizzled

    const int t    = threadIdx.x;
    const int lane = t & 63;
    const int wid  = t >> 6;
    const int wr   = wid >> 1;
    const int wc   = wid & 1;

    const int job = blockIdx.x;
    const bool isV = job < NJV;
    const float* A; const _Float16* WT; int R, r0, ct;
    if (isV) { A = value; WT = wtv;  R = RVr; r0 = (job >> 1) * 64;  ct = job & 1; }
    else     { const int j2 = job - NJV;
               A = query; WT = wtoa; R = RQr; r0 = (j2 / 6) * 64;    ct = j2 % 6; }
    const int c0 = ct * 128;

    f32x4 acc[2][4] = {};

    const int sr = t >> 4;            // 0..15
    const int sc = (t & 15) * 4;      // 0..60
    const int brow  = lane >> 3;                 // 0..7 row-in-chunk
    const int bslot = (lane & 7) ^ brow;         // swizzled 16B source slot

    for (int kc = 0; kc < 256; kc += 64) {
        __syncthreads();
        // B tile: 128n x 64k fp16 = 16KB = 16 chunks of 1KB; wave owns 4.
        #pragma unroll
        for (int cch = 0; cch < 4; ++cch) {
            const int ch  = wid * 4 + cch;
            const int row = ch * 8 + brow;
            const _Float16* src = WT + (size_t)(c0 + row) * 256 + kc + bslot * 8;
            char* ldst = (char*)&bL[0][0] + ch * 1024;
            __builtin_amdgcn_global_load_lds(
                (const __attribute__((address_space(1))) void*)src,
                (__attribute__((address_space(3))) void*)ldst, 16, 0, 0);
        }
        // A tile: 64 x 64 fp32, coalesced float4, convert, 8B LDS writes
        #pragma unroll
        for (int i = 0; i < 4; ++i) {
            const int row = sr + i * 16;
            const int gr  = r0 + row;
            float4 vv = make_float4(0.f, 0.f, 0.f, 0.f);
            if (gr < R) vv = *(const float4*)&A[(size_t)gr * 256 + kc + sc];
            f16x4 pk = { (_Float16)vv.x, (_Float16)vv.y, (_Float16)vv.z, (_Float16)vv.w };
            *(f16x4*)&aL[row][sc] = pk;
        }
        __syncthreads();

        const int lm  = lane & 15;
        const int khi = lane >> 4;
        const char* bB = (const char*)&bL[0][0];
        #pragma unroll
        for (int kk = 0; kk < 2; ++kk) {
            f16x8 bfrag[4];
            #pragma unroll
            for (int nf = 0; nf < 4; ++nf) {
                const int row  = wc * 64 + nf * 16 + lm;
                const int slot = kk * 4 + khi;
                bfrag[nf] = *(const f16x8*)(bB + row * 128 + ((slot ^ (row & 7)) << 4));
            }
            #pragma unroll
            for (int m = 0; m < 2; ++m) {
                const f16x8 afrag = *(const f16x8*)&aL[wr * 32 + m * 16 + lm][kk * 32 + khi * 8];
                #pragma unroll
                for (int nf = 0; nf < 4; ++nf)
                    acc[m][nf] = __builtin_amdgcn_mfma_f32_16x16x32_f16(
                        afrag, bfrag[nf], acc[m][nf], 0, 0, 0);
            }
        }
    }

    const int lm = lane & 15;
    const int lq = lane >> 4;
    if (isV) {
        #pragma unroll
        for (int nf = 0; nf < 4; ++nf) {
            const int col = c0 + wc * 64 + nf * 16 + lm;   // h*32 + ch
            const int hh = col >> 5, ch = col & 31;
            const float bb = bv[col];
            #pragma unroll
            for (int m = 0; m < 2; ++m)
                #pragma unroll
                for (int r = 0; r < 4; ++r) {
                    const int row = r0 + wr * 32 + m * 16 + lq * 4 + r;
                    if (row < RVr) {
                        const int b   = (row >= NVc) ? 1 : 0;
                        const int pix = row - b * NVc;
                        v_f16[(((size_t)(b * HEADS + hh) * NVc) + pix) * 32 + ch] =
                            (_Float16)(acc[m][nf][r] + bb);
                    }
                }
        }
    } else {
        #pragma unroll
        for (int nf = 0; nf < 4; ++nf) {
            const int col = c0 + wc * 64 + nf * 16 + lm;
            const float bb = (col < 512) ? bo[col] : ba[col - 512];
            #pragma unroll
            for (int m = 0; m < 2; ++m)
                #pragma unroll
                for (int r = 0; r < 4; ++r) {
                    const int row = r0 + wr * 32 + m * 16 + lq * 4 + r;
                    if (row < RQr) offa[(size_t)row * 768 + col] = (_Float16)(acc[m][nf][r] + bb);
                }
        }
    }
}

// ---------------------------------------------------------------------------
// Sampling: one wave per task, tasks ordered (b,h)-MAJOR (q fastest): one
// (b,h) v-slab = NVc*64B = 850KB, fits a 4MB per-XCD L2 -> consecutive
// blocks (round-robin across XCDs) keep their slab L2-resident instead of
// streaming all 16 slabs (13.6MB) through every L2.
// v is HEAD-MAJOR: [b][head][pixel][32ch] fp16; x0/x1 corners adjacent 64B.
// Stage 1: lanes j=0..31 per (level,point); halves split corner rows (y0/y1);
// each stores {byte addr, packed half2 weight} int2 into padded LDS.
// Stage 2: 8 iters; lane = (po<<4)|(corner<<2)|octet; 16B fp16 gather;
// pk_fma with fp16 accs; packed 4-level shfl reduction; f32 store.
// ---------------------------------------------------------------------------
__global__ __launch_bounds__(256) void sample_kernel(
    const _Float16* __restrict__ v,    // (B*HEADS*NV) x 32 fp16, head-major
    const _Float16* __restrict__ offa, // (B*NQ) x 768 fp16: [0:512) offsets, [512:768) logits
    const float* __restrict__ refp,    // (B, NQ, NREF, 2)
    float* __restrict__ out)           // (B, NQ, 256)
{
    __shared__ int2 swa[4][32][5];     // {byte addr, packed h2 weight}, padded

    const int t    = threadIdx.x;
    const int wv   = t >> 6;
    const int lane = t & 63;
    const int j    = lane & 31;
    const int half = lane >> 5;

    const int task = blockIdx.x * 4 + wv;   // (b,h)-major: task = bh*NQc + q
    const int bh = task / NQc;              // b*HEADS + h
    const int q  = task - bh * NQc;
    const int h  = bh & 7;
    const int b  = bh >> 3;
    const int bq = b * NQc + q;

    // ---- stage 1 ----
    {
        const int l = j >> 3;
        const int p = j & 7;
        const int r = p & 3;
        const int   Wi = (l == 0) ? 100 : (l == 1) ? 50 : (l == 2) ? 25 : 13;
        const float Wf = (float)Wi;
        const int   st = (l == 0) ? 0 : (l == 1) ? 10000 : (l == 2) ? 12500 : 13125;

        const _Float16* orow = offa + (size_t)bq * 768;
        const float lg = (float)orow[512 + h * 32 + j];
        const float e  = __expf(lg);    // |lg| small: no max-subtraction needed
        float s = e;
        #pragma unroll
        for (int mask = 16; mask >= 1; mask >>= 1)
            s += __shfl_xor(s, mask, 64);
        const float aw = __fdividef(e, s);

        const h2 oxy = *(const h2*)&orow[h * 64 + j * 2];
        const float2 rxy = *(const float2*)&refp[((size_t)bq * NREF + r) * 2];

        const float x = rxy.x * Wf + (float)oxy[0] - 0.5f;
        const float y = rxy.y * Wf + (float)oxy[1] - 0.5f;
        const float x0f = floorf(x), y0f = floorf(y);
        const float dx = x - x0f, dy = y - y0f;
        const int x0 = (int)x0f, y0 = (int)y0f;
        const int x1 = x0 + 1;

        // own corner row for this half
        const int   yy = y0 + half;
        const float fy = (half ? dy : 1.f - dy) * aw;
        const bool  vy = (yy >= 0) && (yy < Wi);
        const int   yc = min(max(yy, 0), Wi - 1);

        const bool vx0 = (x0 >= 0) && (x0 < Wi);
        const bool vx1 = (x1 >= 0) && (x1 < Wi);
        const int  xc0 = min(max(x0, 0), Wi - 1);
        const int  xc1 = min(max(x1, 0), Wi - 1);

        // head-major: pixel stride 64B
        const int bb   = ((b * HEADS + h) * NVc + st) * 64;   // byte base
        const int rowb = bb + yc * Wi * 64;
        const float wA = (vx0 && vy) ? (1.f - dx) * fy : 0.f;
        const float wB = (vx1 && vy) ? dx * fy : 0.f;

        swa[wv][j][half * 2 + 0] = make_int2(rowb + (xc0 << 6), pack2(wA));
        swa[wv][j][half * 2 + 1] = make_int2(rowb + (xc1 << 6), pack2(wB));
    }

    // ---- stage 2 ----
    const int po  = lane >> 4;        // point offset 0..3
    const int c   = (lane >> 2) & 3;  // corner
    const int cqb = (lane & 3) * 16;  // channel-octet byte offset within 64B

    h2 acc0 = {}, acc1 = {}, acc2 = {}, acc3 = {};
    #pragma unroll
    for (int it = 0; it < 8; ++it) {
        const int2 aw2 = swa[wv][it * 4 + po][c];
        const h2 w2 = __builtin_bit_cast(h2, aw2.y);
        const f16x8 val = *(const f16x8*)((const char*)v + aw2.x + cqb);
        acc0 += w2 * (h2){ val[0], val[1] };
        acc1 += w2 * (h2){ val[2], val[3] };
        acc2 += w2 * (h2){ val[4], val[5] };
        acc3 += w2 * (h2){ val[6], val[7] };
    }

    #pragma unroll
    for (int mask = 4; mask <= 32; mask <<= 1) {
        acc0 += __builtin_bit_cast(h2, __shfl_xor(__builtin_bit_cast(int, acc0), mask, 64));
        acc1 += __builtin_bit_cast(h2, __shfl_xor(__builtin_bit_cast(int, acc1), mask, 64));
        acc2 += __builtin_bit_cast(h2, __shfl_xor(__builtin_bit_cast(int, acc2), mask, 64));
        acc3 += __builtin_bit_cast(h2, __shfl_xor(__builtin_bit_cast(int, acc3), mask, 64));
    }

    if (lane < 4) {
        float* dst = &out[(size_t)bq * 256 + h * 32 + lane * 8];
        *(float4*)(dst + 0) = make_float4((float)acc0[0], (float)acc0[1],
                                          (float)acc1[0], (float)acc1[1]);
        *(float4*)(dst + 4) = make_float4((float)acc2[0], (float)acc2[1],
                                          (float)acc3[0], (float)acc3[1]);
    }
}

extern "C" void kernel_launch(void* const* d_in, const int* in_sizes, int n_in,
                              void* d_out, int out_size, void* d_ws, size_t ws_size,
                              hipStream_t stream)
{
    const float* query  = (const float*)d_in[0];
    // d_in[1] = key (unused by the reference)
    const float* value  = (const float*)d_in[2];
    const float* refp   = (const float*)d_in[3];
    const float* Wv     = (const float*)d_in[6];
    const float* bv     = (const float*)d_in[7];
    const float* Wo     = (const float*)d_in[8];
    const float* bo     = (const float*)d_in[9];
    const float* Wa     = (const float*)d_in[10];
    const float* ba     = (const float*)d_in[11];
    float* out = (float*)d_out;

    _Float16* v_f16 = (_Float16*)d_ws;                          // RV*256 f16 (head-major)
    _Float16* offa  = v_f16 + (size_t)RVr * 256;                // RQ*768 f16
    _Float16* wtv   = offa + (size_t)RQr * 768;                 // 256*256 f16
    _Float16* wtoa  = wtv + 256 * 256;                          // 768*256 f16

    transpose_w_kernel<<<dim3(64), 256, 0, stream>>>(
        Wv, Wo, Wa, wtv, wtoa, wtoa + 512 * 256);

    gemm_uber_kernel<<<dim3(NJOBS), 256, 0, stream>>>(
        value, query, wtv, wtoa, bv, bo, ba, v_f16, offa);

    sample_kernel<<<dim3(RQr * HEADS / 4), 256, 0, stream>>>(
        v_f16, offa, refp, out);
}

// Round 11
// 80.641 us; speedup vs baseline: 1.2188x; 1.0163x over previous
//
#include <hip/hip_runtime.h>
#include <math.h>

#define HEADS 8
#define LVLS  4
#define PTS   8
#define NREF  4
#define DH    32
#define DD    256
#define NQc   5000
#define BATCH 2
#define NVc   13294
#define RVr   (BATCH * NVc)   // 26588
#define RQr   (BATCH * NQc)   // 10000

#define NJV 832               // value jobs: 416 row-tiles(64) x 2 col-tiles(128)
#define NJQ 942               // query jobs: 157 row-tiles(64) x 6 col-tiles(128)
#define NJOBS (NJV + NJQ)

using f16x8 = __attribute__((ext_vector_type(8))) _Float16;
using f16x4 = __attribute__((ext_vector_type(4))) _Float16;
using f32x4 = __attribute__((ext_vector_type(4))) float;
using h2    = __attribute__((ext_vector_type(2))) _Float16;

__device__ __forceinline__ int pack2(float w) {
    _Float16 h = (_Float16)w;
    h2 v = { h, h };
    return __builtin_bit_cast(int, v);
}

// ---------------------------------------------------------------------------
// Prep: transpose weights to fp16 W^T[n][k] (k stride 256).
// wtv[256][256]; wtoa[768][256] = concat(Wo^T, Wa^T)
// ---------------------------------------------------------------------------
__global__ __launch_bounds__(256) void transpose_w_kernel(
    const float* __restrict__ Wv, const float* __restrict__ Wo,
    const float* __restrict__ Wa,
    _Float16* __restrict__ wtv, _Float16* __restrict__ wto,
    _Float16* __restrict__ wta)
{
    __shared__ float tl[64][65];
    const int bid = blockIdx.x;
    const float* src; _Float16* dst; int N, kt, nt;
    if (bid < 16)      { src = Wv; dst = wtv; N = 256; kt = bid & 3;        nt = bid >> 2; }
    else if (bid < 48) { src = Wo; dst = wto; N = 512; kt = (bid - 16) & 3; nt = (bid - 16) >> 2; }
    else               { src = Wa; dst = wta; N = 256; kt = (bid - 48) & 3; nt = (bid - 48) >> 2; }
    const int k0 = kt * 64, n0 = nt * 64;
    const int c  = threadIdx.x & 63, r4 = threadIdx.x >> 6;
    #pragma unroll
    for (int i = 0; i < 16; ++i) {
        const int r = r4 + i * 4;
        tl[r][c] = src[(size_t)(k0 + r) * N + n0 + c];
    }
    __syncthreads();
    #pragma unroll
    for (int i = 0; i < 16; ++i) {
        const int r = r4 + i * 4;   // n-local
        dst[(size_t)(n0 + r) * 256 + k0 + c] = (_Float16)tl[c][r];
    }
}

// ---------------------------------------------------------------------------
// Uber MFMA GEMM (R7-proven structure): one dispatch, job table by blockIdx.
//   job < NJV : v_f16 (HEAD-MAJOR: [b][head][NV][32] fp16) = value @ Wv + bv
//   else      : offa[RQ][768](fp16)  = query @ [Wo|Wa] + [bo|ba]
// Tile 64x128, BK=64, 4 waves (2x2), wave tile 32x64, acc 2x4.
// 1774 blocks (~7/CU), 25.6KB LDS: this small-K GEMM is latency-bound ->
// block-level TLP beats per-block density (128x128 variants: 2x slower).
// ---------------------------------------------------------------------------
__global__ __launch_bounds__(256) void gemm_uber_kernel(
    const float* __restrict__ value, const float* __restrict__ query,
    const _Float16* __restrict__ wtv, const _Float16* __restrict__ wtoa,
    const float* __restrict__ bv, const float* __restrict__ bo,
    const float* __restrict__ ba,
    _Float16* __restrict__ v_f16, _Float16* __restrict__ offa)
{
    __shared__ _Float16 aL[64][72];    // 144B row stride
    __shared__ _Float16 bL[128][64];   // [n][k] linear, 16B-slot swizzled

    const int t    = threadIdx.x;
    const int lane = t & 63;
    const int wid  = t >> 6;
    const int wr   = wid >> 1;
    const int wc   = wid & 1;

    const int job = blockIdx.x;
    const bool isV = job < NJV;
    const float* A; const _Float16* WT; int R, r0, ct;
    if (isV) { A = value; WT = wtv;  R = RVr; r0 = (job >> 1) * 64;  ct = job & 1; }
    else     { const int j2 = job - NJV;
               A = query; WT = wtoa; R = RQr; r0 = (j2 / 6) * 64;    ct = j2 % 6; }
    const int c0 = ct * 128;

    f32x4 acc[2][4] = {};

    const int sr = t >> 4;            // 0..15
    const int sc = (t & 15) * 4;      // 0..60
    const int brow  = lane >> 3;                 // 0..7 row-in-chunk
    const int bslot = (lane & 7) ^ brow;         // swizzled 16B source slot

    for (int kc = 0; kc < 256; kc += 64) {
        __syncthreads();
        // B tile: 128n x 64k fp16 = 16KB = 16 chunks of 1KB; wave owns 4.
        #pragma unroll
        for (int cch = 0; cch < 4; ++cch) {
            const int ch  = wid * 4 + cch;
            const int row = ch * 8 + brow;
            const _Float16* src = WT + (size_t)(c0 + row) * 256 + kc + bslot * 8;
            char* ldst = (char*)&bL[0][0] + ch * 1024;
            __builtin_amdgcn_global_load_lds(
                (const __attribute__((address_space(1))) void*)src,
                (__attribute__((address_space(3))) void*)ldst, 16, 0, 0);
        }
        // A tile: 64 x 64 fp32, coalesced float4, convert, 8B LDS writes
        #pragma unroll
        for (int i = 0; i < 4; ++i) {
            const int row = sr + i * 16;
            const int gr  = r0 + row;
            float4 vv = make_float4(0.f, 0.f, 0.f, 0.f);
            if (gr < R) vv = *(const float4*)&A[(size_t)gr * 256 + kc + sc];
            f16x4 pk = { (_Float16)vv.x, (_Float16)vv.y, (_Float16)vv.z, (_Float16)vv.w };
            *(f16x4*)&aL[row][sc] = pk;
        }
        __syncthreads();

        const int lm  = lane & 15;
        const int khi = lane >> 4;
        const char* bB = (const char*)&bL[0][0];
        #pragma unroll
        for (int kk = 0; kk < 2; ++kk) {
            f16x8 bfrag[4];
            #pragma unroll
            for (int nf = 0; nf < 4; ++nf) {
                const int row  = wc * 64 + nf * 16 + lm;
                const int slot = kk * 4 + khi;
                bfrag[nf] = *(const f16x8*)(bB + row * 128 + ((slot ^ (row & 7)) << 4));
            }
            #pragma unroll
            for (int m = 0; m < 2; ++m) {
                const f16x8 afrag = *(const f16x8*)&aL[wr * 32 + m * 16 + lm][kk * 32 + khi * 8];
                #pragma unroll
                for (int nf = 0; nf < 4; ++nf)
                    acc[m][nf] = __builtin_amdgcn_mfma_f32_16x16x32_f16(
                        afrag, bfrag[nf], acc[m][nf], 0, 0, 0);
            }
        }
    }

    const int lm = lane & 15;
    const int lq = lane >> 4;
    if (isV) {
        #pragma unroll
        for (int nf = 0; nf < 4; ++nf) {
            const int col = c0 + wc * 64 + nf * 16 + lm;   // h*32 + ch
            const int hh = col >> 5, ch = col & 31;
            const float bb = bv[col];
            #pragma unroll
            for (int m = 0; m < 2; ++m)
                #pragma unroll
                for (int r = 0; r < 4; ++r) {
                    const int row = r0 + wr * 32 + m * 16 + lq * 4 + r;
                    if (row < RVr) {
                        const int b   = (row >= NVc) ? 1 : 0;
                        const int pix = row - b * NVc;
                        v_f16[(((size_t)(b * HEADS + hh) * NVc) + pix) * 32 + ch] =
                            (_Float16)(acc[m][nf][r] + bb);
                    }
                }
        }
    } else {
        #pragma unroll
        for (int nf = 0; nf < 4; ++nf) {
            const int col = c0 + wc * 64 + nf * 16 + lm;
            const float bb = (col < 512) ? bo[col] : ba[col - 512];
            #pragma unroll
            for (int m = 0; m < 2; ++m)
                #pragma unroll
                for (int r = 0; r < 4; ++r) {
                    const int row = r0 + wr * 32 + m * 16 + lq * 4 + r;
                    if (row < RQr) offa[(size_t)row * 768 + col] = (_Float16)(acc[m][nf][r] + bb);
                }
        }
    }
}

// ---------------------------------------------------------------------------
// Sampling: one wave per (b, q, h), bq-major (8 h-tasks of one bq adjacent ->
// offa row shared in-block; R10 showed slab-major order is time-neutral but
// adds 23MB HBM). v HEAD-MAJOR [b][head][pixel][32ch]; x0/x1 corners adjacent.
// Stage 1: lanes j=0..31 per (level,point); halves split corner rows (y0/y1).
// Stage 2 EXPLICITLY 3-PHASE (R10 showed VGPR=32 -> only ~2 gathers in
// flight, latency-bound): (a) all 8 LDS descriptor reads -> regs, (b) all 8
// independent 16B global loads issued back-to-back, (c) 32 pk_fma.
// ---------------------------------------------------------------------------
__global__ __launch_bounds__(256) void sample_kernel(
    const _Float16* __restrict__ v,    // (B*HEADS*NV) x 32 fp16, head-major
    const _Float16* __restrict__ offa, // (B*NQ) x 768 fp16: [0:512) offsets, [512:768) logits
    const float* __restrict__ refp,    // (B, NQ, NREF, 2)
    float* __restrict__ out)           // (B, NQ, 256)
{
    __shared__ int2 swa[4][32][5];     // {byte addr, packed h2 weight}, padded

    const int t    = threadIdx.x;
    const int wv   = t >> 6;
    const int lane = t & 63;
    const int j    = lane & 31;
    const int half = lane >> 5;

    const int task = blockIdx.x * 4 + wv;       // bq-major: task = bq*8 + h
    const int h  = task & 7;
    const int bq = task >> 3;
    const int b  = bq / NQc;

    // ---- stage 1 ----
    {
        const int l = j >> 3;
        const int p = j & 7;
        const int r = p & 3;
        const int   Wi = (l == 0) ? 100 : (l == 1) ? 50 : (l == 2) ? 25 : 13;
        const float Wf = (float)Wi;
        const int   st = (l == 0) ? 0 : (l == 1) ? 10000 : (l == 2) ? 12500 : 13125;

        const _Float16* orow = offa + (size_t)bq * 768;
        const float lg = (float)orow[512 + h * 32 + j];
        const float e  = __expf(lg);    // |lg| small: no max-subtraction needed
        float s = e;
        #pragma unroll
        for (int mask = 16; mask >= 1; mask >>= 1)
            s += __shfl_xor(s, mask, 64);
        const float aw = __fdividef(e, s);

        const h2 oxy = *(const h2*)&orow[h * 64 + j * 2];
        const float2 rxy = *(const float2*)&refp[((size_t)bq * NREF + r) * 2];

        const float x = rxy.x * Wf + (float)oxy[0] - 0.5f;
        const float y = rxy.y * Wf + (float)oxy[1] - 0.5f;
        const float x0f = floorf(x), y0f = floorf(y);
        const float dx = x - x0f, dy = y - y0f;
        const int x0 = (int)x0f, y0 = (int)y0f;
        const int x1 = x0 + 1;

        // own corner row for this half
        const int   yy = y0 + half;
        const float fy = (half ? dy : 1.f - dy) * aw;
        const bool  vy = (yy >= 0) && (yy < Wi);
        const int   yc = min(max(yy, 0), Wi - 1);

        const bool vx0 = (x0 >= 0) && (x0 < Wi);
        const bool vx1 = (x1 >= 0) && (x1 < Wi);
        const int  xc0 = min(max(x0, 0), Wi - 1);
        const int  xc1 = min(max(x1, 0), Wi - 1);

        // head-major: pixel stride 64B
        const int bb   = ((b * HEADS + h) * NVc + st) * 64;   // byte base
        const int rowb = bb + yc * Wi * 64;
        const float wA = (vx0 && vy) ? (1.f - dx) * fy : 0.f;
        const float wB = (vx1 && vy) ? dx * fy : 0.f;

        swa[wv][j][half * 2 + 0] = make_int2(rowb + (xc0 << 6), pack2(wA));
        swa[wv][j][half * 2 + 1] = make_int2(rowb + (xc1 << 6), pack2(wB));
    }

    // ---- stage 2: 3-phase, 8 loads in flight ----
    const int po  = lane >> 4;        // point offset 0..3
    const int c   = (lane >> 2) & 3;  // corner
    const int cqb = (lane & 3) * 16;  // channel-octet byte offset within 64B

    int2 aw8[8];
    #pragma unroll
    for (int it = 0; it < 8; ++it)
        aw8[it] = swa[wv][it * 4 + po][c];

    f16x8 val[8];
    #pragma unroll
    for (int it = 0; it < 8; ++it)
        val[it] = *(const f16x8*)((const char*)v + aw8[it].x + cqb);

    h2 acc0 = {}, acc1 = {}, acc2 = {}, acc3 = {};
    #pragma unroll
    for (int it = 0; it < 8; ++it) {
        const h2 w2 = __builtin_bit_cast(h2, aw8[it].y);
        acc0 += w2 * (h2){ val[it][0], val[it][1] };
        acc1 += w2 * (h2){ val[it][2], val[it][3] };
        acc2 += w2 * (h2){ val[it][4], val[it][5] };
        acc3 += w2 * (h2){ val[it][6], val[it][7] };
    }

    #pragma unroll
    for (int mask = 4; mask <= 32; mask <<= 1) {
        acc0 += __builtin_bit_cast(h2, __shfl_xor(__builtin_bit_cast(int, acc0), mask, 64));
        acc1 += __builtin_bit_cast(h2, __shfl_xor(__builtin_bit_cast(int, acc1), mask, 64));
        acc2 += __builtin_bit_cast(h2, __shfl_xor(__builtin_bit_cast(int, acc2), mask, 64));
        acc3 += __builtin_bit_cast(h2, __shfl_xor(__builtin_bit_cast(int, acc3), mask, 64));
    }

    if (lane < 4) {
        float* dst = &out[(size_t)bq * 256 + h * 32 + lane * 8];
        *(float4*)(dst + 0) = make_float4((float)acc0[0], (float)acc0[1],
                                          (float)acc1[0], (float)acc1[1]);
        *(float4*)(dst + 4) = make_float4((float)acc2[0], (float)acc2[1],
                                          (float)acc3[0], (float)acc3[1]);
    }
}

extern "C" void kernel_launch(void* const* d_in, const int* in_sizes, int n_in,
                              void* d_out, int out_size, void* d_ws, size_t ws_size,
                              hipStream_t stream)
{
    const float* query  = (const float*)d_in[0];
    // d_in[1] = key (unused by the reference)
    const float* value  = (const float*)d_in[2];
    const float* refp   = (const float*)d_in[3];
    const float* Wv     = (const float*)d_in[6];
    const float* bv     = (const float*)d_in[7];
    const float* Wo     = (const float*)d_in[8];
    const float* bo     = (const float*)d_in[9];
    const float* Wa     = (const float*)d_in[10];
    const float* ba     = (const float*)d_in[11];
    float* out = (float*)d_out;

    _Float16* v_f16 = (_Float16*)d_ws;                          // RV*256 f16 (head-major)
    _Float16* offa  = v_f16 + (size_t)RVr * 256;                // RQ*768 f16
    _Float16* wtv   = offa + (size_t)RQr * 768;                 // 256*256 f16
    _Float16* wtoa  = wtv + 256 * 256;                          // 768*256 f16

    transpose_w_kernel<<<dim3(64), 256, 0, stream>>>(
        Wv, Wo, Wa, wtv, wtoa, wtoa + 512 * 256);

    gemm_uber_kernel<<<dim3(NJOBS), 256, 0, stream>>>(
        value, query, wtv, wtoa, bv, bo, ba, v_f16, offa);

    sample_kernel<<<dim3(RQr * HEADS / 4), 256, 0, stream>>>(
        v_f16, offa, refp, out);
}

// Round 12
// 76.563 us; speedup vs baseline: 1.2837x; 1.0533x over previous
//
#include <hip/hip_runtime.h>
#include <math.h>

#define HEADS 8
#define LVLS  4
#define PTS   8
#define NREF  4
#define DH    32
#define DD    256
#define NQc   5000
#define BATCH 2
#define NVc   13294
#define RVr   (BATCH * NVc)   // 26588
#define RQr   (BATCH * NQc)   // 10000

#define NJV 832               // value jobs: 416 row-tiles(64) x 2 col-tiles(128)
#define NJQ 942               // query jobs: 157 row-tiles(64) x 6 col-tiles(128)
#define NJOBS (NJV + NJQ)

#define NEV (RVr * 256)       // 6806528 value elems
#define NEQ (RQr * 256)       // 2560000 query elems
#define NCV ((NEV + 4095) / 4096)   // 1662 convert blocks (value)
#define NCQ ((NEQ + 4095) / 4096)   // 625  convert blocks (query)

using f16x8 = __attribute__((ext_vector_type(8))) _Float16;
using f16x4 = __attribute__((ext_vector_type(4))) _Float16;
using f32x4 = __attribute__((ext_vector_type(4))) float;
using h2    = __attribute__((ext_vector_type(2))) _Float16;

__device__ __forceinline__ int pack2(float w) {
    _Float16 h = (_Float16)w;
    h2 v = { h, h };
    return __builtin_bit_cast(int, v);
}

// ---------------------------------------------------------------------------
// Prep (one dispatch): [0,64) transpose weights to fp16 W^T[n][k];
// [64,...) stream-convert value & query f32 -> fp16 (same row-major layout).
// ---------------------------------------------------------------------------
__global__ __launch_bounds__(256) void prep_kernel(
    const float* __restrict__ value, const float* __restrict__ query,
    const float* __restrict__ Wv, const float* __restrict__ Wo,
    const float* __restrict__ Wa,
    _Float16* __restrict__ a16v, _Float16* __restrict__ a16q,
    _Float16* __restrict__ wtv, _Float16* __restrict__ wto,
    _Float16* __restrict__ wta)
{
    const int bid = blockIdx.x;
    const int t   = threadIdx.x;
    if (bid < 64) {
        __shared__ float tl[64][65];
        const float* src; _Float16* dst; int N, kt, nt;
        if (bid < 16)      { src = Wv; dst = wtv; N = 256; kt = bid & 3;        nt = bid >> 2; }
        else if (bid < 48) { src = Wo; dst = wto; N = 512; kt = (bid - 16) & 3; nt = (bid - 16) >> 2; }
        else               { src = Wa; dst = wta; N = 256; kt = (bid - 48) & 3; nt = (bid - 48) >> 2; }
        const int k0 = kt * 64, n0 = nt * 64;
        const int c  = t & 63, r4 = t >> 6;
        #pragma unroll
        for (int i = 0; i < 16; ++i) {
            const int r = r4 + i * 4;
            tl[r][c] = src[(size_t)(k0 + r) * N + n0 + c];
        }
        __syncthreads();
        #pragma unroll
        for (int i = 0; i < 16; ++i) {
            const int r = r4 + i * 4;   // n-local
            dst[(size_t)(n0 + r) * 256 + k0 + c] = (_Float16)tl[c][r];
        }
        return;
    }
    // stream conversion: 4096 elems per block
    const int cid = bid - 64;
    const float* src; _Float16* dst; int n; size_t base;
    if (cid < NCV) { src = value; dst = a16v; n = NEV; base = (size_t)cid * 4096; }
    else           { src = query; dst = a16q; n = NEQ; base = (size_t)(cid - NCV) * 4096; }
    #pragma unroll
    for (int i = 0; i < 4; ++i) {
        const size_t idx = base + i * 1024 + t * 4;
        if (idx < (size_t)n) {
            const float4 v = *(const float4*)&src[idx];
            f16x4 pk = { (_Float16)v.x, (_Float16)v.y, (_Float16)v.z, (_Float16)v.w };
            *(f16x4*)&dst[idx] = pk;
        }
    }
}

// ---------------------------------------------------------------------------
// Uber MFMA GEMM: both operands staged via global_load_lds (A pre-converted
// to fp16 by prep) -> zero VALU staging inside the K-loop.
//   job < NJV : v_f16 (HEAD-MAJOR: [b][head][NV][32] fp16) = value @ Wv + bv
//   else      : offa[RQ][768](fp16)  = query @ [Wo|Wa] + [bo|ba]
// Tile 64x128, BK=64, 4 waves (2x2), wave tile 32x64, acc 2x4. LDS 24KB.
// Both A and B: [row][64k] fp16 linear, 16B-slot XOR-swizzled source
// (slot ^= row&7), frag reads apply the same XOR. A-tail rows (>=R) read
// garbage from adjacent ws (allocated) and are discarded in the epilogue.
// ---------------------------------------------------------------------------
__global__ __launch_bounds__(256) void gemm_uber_kernel(
    const _Float16* __restrict__ a16v, const _Float16* __restrict__ a16q,
    const _Float16* __restrict__ wtv, const _Float16* __restrict__ wtoa,
    const float* __restrict__ bv, const float* __restrict__ bo,
    const float* __restrict__ ba,
    _Float16* __restrict__ v_f16, _Float16* __restrict__ offa)
{
    __shared__ _Float16 aL[64][64];    // [row][k] linear, swizzled slots
    __shared__ _Float16 bL[128][64];   // [n][k]  linear, swizzled slots

    const int t    = threadIdx.x;
    const int lane = t & 63;
    const int wid  = t >> 6;
    const int wr   = wid >> 1;
    const int wc   = wid & 1;

    const int job = blockIdx.x;
    const bool isV = job < NJV;
    const _Float16* A; const _Float16* WT; int r0, ct;
    if (isV) { A = a16v; WT = wtv;  r0 = (job >> 1) * 64;  ct = job & 1; }
    else     { const int j2 = job - NJV;
               A = a16q; WT = wtoa; r0 = (j2 / 6) * 64;    ct = j2 % 6; }
    const int c0 = ct * 128;

    f32x4 acc[2][4] = {};

    const int brow  = lane >> 3;                 // 0..7 row-in-chunk
    const int bslot = (lane & 7) ^ brow;         // swizzled 16B source slot
    const int lm  = lane & 15;
    const int khi = lane >> 4;

    for (int kc = 0; kc < 256; kc += 64) {
        __syncthreads();
        // B tile: 128n x 64k = 16KB = 16 chunks of 1KB; wave owns 4.
        #pragma unroll
        for (int cch = 0; cch < 4; ++cch) {
            const int ch  = wid * 4 + cch;
            const int row = ch * 8 + brow;
            const _Float16* src = WT + (size_t)(c0 + row) * 256 + kc + bslot * 8;
            char* ldst = (char*)&bL[0][0] + ch * 1024;
            __builtin_amdgcn_global_load_lds(
                (const __attribute__((address_space(1))) void*)src,
                (__attribute__((address_space(3))) void*)ldst, 16, 0, 0);
        }
        // A tile: 64r x 64k = 8KB = 8 chunks of 1KB; wave owns 2.
        #pragma unroll
        for (int cch = 0; cch < 2; ++cch) {
            const int ch  = wid * 2 + cch;
            const int row = ch * 8 + brow;
            const _Float16* src = A + (size_t)(r0 + row) * 256 + kc + bslot * 8;
            char* ldst = (char*)&aL[0][0] + ch * 1024;
            __builtin_amdgcn_global_load_lds(
                (const __attribute__((address_space(1))) void*)src,
                (__attribute__((address_space(3))) void*)ldst, 16, 0, 0);
        }
        __syncthreads();

        const char* bB = (const char*)&bL[0][0];
        const char* aB = (const char*)&aL[0][0];
        #pragma unroll
        for (int kk = 0; kk < 2; ++kk) {
            const int slot = kk * 4 + khi;
            f16x8 bfrag[4];
            #pragma unroll
            for (int nf = 0; nf < 4; ++nf) {
                const int row = wc * 64 + nf * 16 + lm;
                bfrag[nf] = *(const f16x8*)(bB + row * 128 + ((slot ^ (row & 7)) << 4));
            }
            #pragma unroll
            for (int m = 0; m < 2; ++m) {
                const int arow = wr * 32 + m * 16 + lm;
                const f16x8 afrag = *(const f16x8*)(aB + arow * 128 + ((slot ^ (arow & 7)) << 4));
                #pragma unroll
                for (int nf = 0; nf < 4; ++nf)
                    acc[m][nf] = __builtin_amdgcn_mfma_f32_16x16x32_f16(
                        afrag, bfrag[nf], acc[m][nf], 0, 0, 0);
            }
        }
    }

    const int lq = lane >> 4;
    if (isV) {
        #pragma unroll
        for (int nf = 0; nf < 4; ++nf) {
            const int col = c0 + wc * 64 + nf * 16 + lm;   // h*32 + ch
            const int hh = col >> 5, ch = col & 31;
            const float bb = bv[col];
            #pragma unroll
            for (int m = 0; m < 2; ++m)
                #pragma unroll
                for (int r = 0; r < 4; ++r) {
                    const int row = r0 + wr * 32 + m * 16 + lq * 4 + r;
                    if (row < RVr) {
                        const int b   = (row >= NVc) ? 1 : 0;
                        const int pix = row - b * NVc;
                        v_f16[(((size_t)(b * HEADS + hh) * NVc) + pix) * 32 + ch] =
                            (_Float16)(acc[m][nf][r] + bb);
                    }
                }
        }
    } else {
        #pragma unroll
        for (int nf = 0; nf < 4; ++nf) {
            const int col = c0 + wc * 64 + nf * 16 + lm;
            const float bb = (col < 512) ? bo[col] : ba[col - 512];
            #pragma unroll
            for (int m = 0; m < 2; ++m)
                #pragma unroll
                for (int r = 0; r < 4; ++r) {
                    const int row = r0 + wr * 32 + m * 16 + lq * 4 + r;
                    if (row < RQr) offa[(size_t)row * 768 + col] = (_Float16)(acc[m][nf][r] + bb);
                }
        }
    }
}

// ---------------------------------------------------------------------------
// Sampling (unchanged from R11): one wave per (b, q, h), bq-major.
// v HEAD-MAJOR [b][head][pixel][32ch]; x0/x1 corners adjacent 64B.
// ---------------------------------------------------------------------------
__global__ __launch_bounds__(256) void sample_kernel(
    const _Float16* __restrict__ v,    // (B*HEADS*NV) x 32 fp16, head-major
    const _Float16* __restrict__ offa, // (B*NQ) x 768 fp16: [0:512) offsets, [512:768) logits
    const float* __restrict__ refp,    // (B, NQ, NREF, 2)
    float* __restrict__ out)           // (B, NQ, 256)
{
    __shared__ int2 swa[4][32][5];     // {byte addr, packed h2 weight}, padded

    const int t    = threadIdx.x;
    const int wv   = t >> 6;
    const int lane = t & 63;
    const int j    = lane & 31;
    const int half = lane >> 5;

    const int task = blockIdx.x * 4 + wv;       // bq-major: task = bq*8 + h
    const int h  = task & 7;
    const int bq = task >> 3;
    const int b  = bq / NQc;

    // ---- stage 1 ----
    {
        const int l = j >> 3;
        const int p = j & 7;
        const int r = p & 3;
        const int   Wi = (l == 0) ? 100 : (l == 1) ? 50 : (l == 2) ? 25 : 13;
        const float Wf = (float)Wi;
        const int   st = (l == 0) ? 0 : (l == 1) ? 10000 : (l == 2) ? 12500 : 13125;

        const _Float16* orow = offa + (size_t)bq * 768;
        const float lg = (float)orow[512 + h * 32 + j];
        const float e  = __expf(lg);    // |lg| small: no max-subtraction needed
        float s = e;
        #pragma unroll
        for (int mask = 16; mask >= 1; mask >>= 1)
            s += __shfl_xor(s, mask, 64);
        const float aw = __fdividef(e, s);

        const h2 oxy = *(const h2*)&orow[h * 64 + j * 2];
        const float2 rxy = *(const float2*)&refp[((size_t)bq * NREF + r) * 2];

        const float x = rxy.x * Wf + (float)oxy[0] - 0.5f;
        const float y = rxy.y * Wf + (float)oxy[1] - 0.5f;
        const float x0f = floorf(x), y0f = floorf(y);
        const float dx = x - x0f, dy = y - y0f;
        const int x0 = (int)x0f, y0 = (int)y0f;
        const int x1 = x0 + 1;

        const int   yy = y0 + half;
        const float fy = (half ? dy : 1.f - dy) * aw;
        const bool  vy = (yy >= 0) && (yy < Wi);
        const int   yc = min(max(yy, 0), Wi - 1);

        const bool vx0 = (x0 >= 0) && (x0 < Wi);
        const bool vx1 = (x1 >= 0) && (x1 < Wi);
        const int  xc0 = min(max(x0, 0), Wi - 1);
        const int  xc1 = min(max(x1, 0), Wi - 1);

        const int bb   = ((b * HEADS + h) * NVc + st) * 64;   // byte base
        const int rowb = bb + yc * Wi * 64;
        const float wA = (vx0 && vy) ? (1.f - dx) * fy : 0.f;
        const float wB = (vx1 && vy) ? dx * fy : 0.f;

        swa[wv][j][half * 2 + 0] = make_int2(rowb + (xc0 << 6), pack2(wA));
        swa[wv][j][half * 2 + 1] = make_int2(rowb + (xc1 << 6), pack2(wB));
    }

    // ---- stage 2 ----
    const int po  = lane >> 4;        // point offset 0..3
    const int c   = (lane >> 2) & 3;  // corner
    const int cqb = (lane & 3) * 16;  // channel-octet byte offset within 64B

    int2 aw8[8];
    #pragma unroll
    for (int it = 0; it < 8; ++it)
        aw8[it] = swa[wv][it * 4 + po][c];

    f16x8 val[8];
    #pragma unroll
    for (int it = 0; it < 8; ++it)
        val[it] = *(const f16x8*)((const char*)v + aw8[it].x + cqb);

    h2 acc0 = {}, acc1 = {}, acc2 = {}, acc3 = {};
    #pragma unroll
    for (int it = 0; it < 8; ++it) {
        const h2 w2 = __builtin_bit_cast(h2, aw8[it].y);
        acc0 += w2 * (h2){ val[it][0], val[it][1] };
        acc1 += w2 * (h2){ val[it][2], val[it][3] };
        acc2 += w2 * (h2){ val[it][4], val[it][5] };
        acc3 += w2 * (h2){ val[it][6], val[it][7] };
    }

    #pragma unroll
    for (int mask = 4; mask <= 32; mask <<= 1) {
        acc0 += __builtin_bit_cast(h2, __shfl_xor(__builtin_bit_cast(int, acc0), mask, 64));
        acc1 += __builtin_bit_cast(h2, __shfl_xor(__builtin_bit_cast(int, acc1), mask, 64));
        acc2 += __builtin_bit_cast(h2, __shfl_xor(__builtin_bit_cast(int, acc2), mask, 64));
        acc3 += __builtin_bit_cast(h2, __shfl_xor(__builtin_bit_cast(int, acc3), mask, 64));
    }

    if (lane < 4) {
        float* dst = &out[(size_t)bq * 256 + h * 32 + lane * 8];
        *(float4*)(dst + 0) = make_float4((float)acc0[0], (float)acc0[1],
                                          (float)acc1[0], (float)acc1[1]);
        *(float4*)(dst + 4) = make_float4((float)acc2[0], (float)acc2[1],
                                          (float)acc3[0], (float)acc3[1]);
    }
}

extern "C" void kernel_launch(void* const* d_in, const int* in_sizes, int n_in,
                              void* d_out, int out_size, void* d_ws, size_t ws_size,
                              hipStream_t stream)
{
    const float* query  = (const float*)d_in[0];
    // d_in[1] = key (unused by the reference)
    const float* value  = (const float*)d_in[2];
    const float* refp   = (const float*)d_in[3];
    const float* Wv     = (const float*)d_in[6];
    const float* bv     = (const float*)d_in[7];
    const float* Wo     = (const float*)d_in[8];
    const float* bo     = (const float*)d_in[9];
    const float* Wa     = (const float*)d_in[10];
    const float* ba     = (const float*)d_in[11];
    float* out = (float*)d_out;

    // ws layout (fp16 elems). a16q must not be last: GEMM A-tail reads
    // spill a few rows past each region into the next (allocated) one.
    _Float16* a16v  = (_Float16*)d_ws;                          // RV*256
    _Float16* a16q  = a16v + (size_t)RVr * 256;                 // RQ*256
    _Float16* v_f16 = a16q + (size_t)RQr * 256;                 // RV*256 (head-major)
    _Float16* offa  = v_f16 + (size_t)RVr * 256;                // RQ*768
    _Float16* wtv   = offa + (size_t)RQr * 768;                 // 256*256
    _Float16* wtoa  = wtv + 256 * 256;                          // 768*256

    prep_kernel<<<dim3(64 + NCV + NCQ), 256, 0, stream>>>(
        value, query, Wv, Wo, Wa, a16v, a16q, wtv, wtoa, wtoa + 512 * 256);

    gemm_uber_kernel<<<dim3(NJOBS), 256, 0, stream>>>(
        a16v, a16q, wtv, wtoa, bv, bo, ba, v_f16, offa);

    sample_kernel<<<dim3(RQr * HEADS / 4), 256, 0, stream>>>(
        v_f16, offa, refp, out);
}